// Round 7
// baseline (406.580 us; speedup 1.0000x reference)
//
#include <hip/hip_runtime.h>

// Neurcomp / SIREN MLP inference — round 7.
// Round 6 (378 us): MfmaUtil 33% (=125 us, the 3-split MFMA floor),
// VALUBusy 44% (=166 us) -> VALU-limited by FRAGS hi/lo unpacking
// (256 ops/layer/lane) + packf; occupancy 6 waves/CU (LDS 67.6 KB).
// Changes: (1) activations stored as SEPARATE hi/lo bf16 LDS planes
// ([32][136] u16, 17x16B rows -> conflict-free b128) so ds_read_b128
// yields MFMA A-fragments directly (FRAGS deleted); (2) 1-wave blocks
// (BT=64, 17.4 KB LDS) -> ~9 waves/CU for MFMA/VALU/DS overlap.
// Layouts (verified): A[m=lane&15][k=(lane>>4)*8+j],
// B[k=(lane>>4)*8+j][n=lane&15], C/D col=lane&15 row=(lane>>4)*4+reg.

typedef unsigned int u32;
typedef short s8v __attribute__((ext_vector_type(8)));   // 8 bf16 (bits)
typedef float f4v __attribute__((ext_vector_type(4)));
typedef u32   u4v __attribute__((ext_vector_type(4)));

constexpr float OMEGA = 30.0f;
constexpr int HID = 128, NRES = 7, BT = 64;
constexpr int RSTR = 136;               // u16 per plane row (17 x 16B)
constexpr int FRAG_ELEMS = 14 * 16384;  // bf16 elems per hi/lo ws array

__device__ __forceinline__ float sin_om(float z) {
    float r = z * (OMEGA * 0.15915494309189535f);
    r = r - floorf(r);
    return __builtin_amdgcn_sinf(r);
}

__device__ __forceinline__ f4v mfma16(s8v a, s8v b, f4v c) {
    return __builtin_amdgcn_mfma_f32_16x16x32_bf16(a, b, c, 0, 0, 0);
}

// split fp32 value into hi/lo bf16 planes at u16 index a_
#define SPLIT(val_, a_) { float sf_ = (val_); \
    u32 sb_ = __builtin_bit_cast(u32, sf_); \
    u32 shb_ = sb_ & 0xffff0000u; \
    float sl_ = sf_ - __builtin_bit_cast(float, shb_); \
    PHI[a_] = (unsigned short)(sb_ >> 16); \
    PLO[a_] = (unsigned short)(__builtin_bit_cast(u32, sl_) >> 16); }

// ---- repetition lists ----
#define LMR8(M) M(0,0) M(0,1) M(0,2) M(0,3) M(1,0) M(1,1) M(1,2) M(1,3)
#define LNT8(M) M(0) M(1) M(2) M(3) M(4) M(5) M(6) M(7)
#define LAF8(M) M(0,0) M(0,1) M(0,2) M(0,3) M(1,0) M(1,1) M(1,2) M(1,3)
#define LH64(M) \
  M(0,0,0) M(0,0,1) M(0,0,2) M(0,0,3) M(0,1,0) M(0,1,1) M(0,1,2) M(0,1,3) \
  M(0,2,0) M(0,2,1) M(0,2,2) M(0,2,3) M(0,3,0) M(0,3,1) M(0,3,2) M(0,3,3) \
  M(0,4,0) M(0,4,1) M(0,4,2) M(0,4,3) M(0,5,0) M(0,5,1) M(0,5,2) M(0,5,3) \
  M(0,6,0) M(0,6,1) M(0,6,2) M(0,6,3) M(0,7,0) M(0,7,1) M(0,7,2) M(0,7,3) \
  M(1,0,0) M(1,0,1) M(1,0,2) M(1,0,3) M(1,1,0) M(1,1,1) M(1,1,2) M(1,1,3) \
  M(1,2,0) M(1,2,1) M(1,2,2) M(1,2,3) M(1,3,0) M(1,3,1) M(1,3,2) M(1,3,3) \
  M(1,4,0) M(1,4,1) M(1,4,2) M(1,4,3) M(1,5,0) M(1,5,1) M(1,5,2) M(1,5,3) \
  M(1,6,0) M(1,6,1) M(1,6,2) M(1,6,3) M(1,7,0) M(1,7,1) M(1,7,2) M(1,7,3)
#define LT8(M) \
  M(0, H_0_0_0,H_0_0_1,H_0_0_2,H_0_0_3, H_1_0_0,H_1_0_1,H_1_0_2,H_1_0_3) \
  M(1, H_0_1_0,H_0_1_1,H_0_1_2,H_0_1_3, H_1_1_0,H_1_1_1,H_1_1_2,H_1_1_3) \
  M(2, H_0_2_0,H_0_2_1,H_0_2_2,H_0_2_3, H_1_2_0,H_1_2_1,H_1_2_2,H_1_2_3) \
  M(3, H_0_3_0,H_0_3_1,H_0_3_2,H_0_3_3, H_1_3_0,H_1_3_1,H_1_3_2,H_1_3_3) \
  M(4, H_0_4_0,H_0_4_1,H_0_4_2,H_0_4_3, H_1_4_0,H_1_4_1,H_1_4_2,H_1_4_3) \
  M(5, H_0_5_0,H_0_5_1,H_0_5_2,H_0_5_3, H_1_5_0,H_1_5_1,H_1_5_2,H_1_5_3) \
  M(6, H_0_6_0,H_0_6_1,H_0_6_2,H_0_6_3, H_1_6_0,H_1_6_1,H_1_6_2,H_1_6_3) \
  M(7, H_0_7_0,H_0_7_1,H_0_7_2,H_0_7_3, H_1_7_0,H_1_7_1,H_1_7_2,H_1_7_3)

// ---- weight prep: fp32 W -> hi/lo bf16 B-fragments in d_ws ----
// frag elem offset for (L,t,kc,lane,j) = 8*(L*2048 + t*256 + kc*64 + lane) + j
__global__ void prep_kernel(const float* __restrict__ rw1,
                            const float* __restrict__ rw2,
                            unsigned short* __restrict__ wsHi,
                            unsigned short* __restrict__ wsLo) {
    int id = blockIdx.x * 256 + threadIdx.x;      // 0 .. 28671
    int lane = id & 63, kc = (id >> 6) & 3, t = (id >> 8) & 7, L = id >> 11;
    int i = L >> 1;
    bool isW1 = ((L & 1) == 0);
    const float* W = (isW1 ? rw1 : rw2) + i * HID * HID;
    float sc = (isW1 && i > 0) ? 0.5f : 1.0f;     // fold wgt1 (ave_first)
    int n = t * 16 + (lane & 15);                  // output feature
    int k0 = kc * 32 + (lane >> 4) * 8;            // input feature base
    const float* src = W + n * HID + k0;           // W[n][k0..k0+7]
    int off = id * 8;
    for (int j = 0; j < 8; ++j) {
        float w = src[j] * sc;
        u32 b = __builtin_bit_cast(u32, w);
        u32 hb = b & 0xffff0000u;
        float lo = w - __builtin_bit_cast(float, hb);
        wsHi[off + j] = (unsigned short)(b >> 16);
        wsLo[off + j] = (unsigned short)(__builtin_bit_cast(u32, lo) >> 16);
    }
}

__global__ void __launch_bounds__(BT)
__attribute__((amdgpu_waves_per_eu(2)))
siren_mfma(const float* __restrict__ x,
           const float* __restrict__ w0p, const float* __restrict__ b0p,
           const float* __restrict__ b1p, const float* __restrict__ b2p,
           const float* __restrict__ wfp, const float* __restrict__ bfp,
           const u4v* __restrict__ whi, const u4v* __restrict__ wlo,
           float* __restrict__ out, int NP)
{
    __shared__ unsigned short PHI[32 * RSTR];      // hi bf16 plane, 8704 B
    __shared__ unsigned short PLO[32 * RSTR];      // lo bf16 plane, 8704 B

    const int lane = threadIdx.x & 63;
    const int ln = lane & 15, q = lane >> 4;
    const int q4 = q * 4, q8 = q * 8;
    const int base_pt = blockIdx.x * 32;

    // ---- first SineLayer (fp32 VALU), H in C-layout named registers ----
#define LX(mt,reg) float X_##mt##_##reg, Y_##mt##_##reg, Z_##mt##_##reg; \
    { int pt_ = base_pt + mt*16 + q4 + reg; int ix_ = pt_ < NP ? pt_ : NP-1; \
      X_##mt##_##reg = x[3*ix_+0]; Y_##mt##_##reg = x[3*ix_+1]; \
      Z_##mt##_##reg = x[3*ix_+2]; }
    LMR8(LX)
#define LW(nt) float WA##nt = w0p[3*(nt*16+ln)+0], WB##nt = w0p[3*(nt*16+ln)+1], \
    WC##nt = w0p[3*(nt*16+ln)+2], BB##nt = b0p[nt*16+ln];
    LNT8(LW)
#define FL0(mt,nt,reg) float H_##mt##_##nt##_##reg = sin_om( \
    fmaf(WA##nt, X_##mt##_##reg, fmaf(WB##nt, Y_##mt##_##reg, \
    fmaf(WC##nt, Z_##mt##_##reg, BB##nt))));
    LH64(FL0)

    // A-fragment registers (hi/lo) for 2 M-tiles x 4 k-chunks
    s8v FH00, FH01, FH02, FH03, FH10, FH11, FH12, FH13;
    s8v FL00, FL01, FL02, FL03, FL10, FL11, FL12, FL13;

    // h (C-layout regs) -> hi/lo planes [m=point][k=feature]
#define WH(mt,nt,reg) SPLIT(H_##mt##_##nt##_##reg, \
    (mt*16 + q4 + reg)*RSTR + nt*16 + ln)
    // A-fragments: b128 on each plane directly yields short8
#define RF(mt,kc) { const int a_ = (mt*16+ln)*RSTR + kc*32 + q8; \
    FH##mt##kc = *(const s8v*)&PHI[a_]; \
    FL##mt##kc = *(const s8v*)&PLO[a_]; }

#define ST5(t, ea0,ea1,ea2,ea3, eb0,eb1,eb2,eb3) { \
    const int fb = (L2*32 + t*4)*64 + lane; \
    u4v g0 = whi[fb], g1 = whi[fb+64], g2 = whi[fb+128], g3 = whi[fb+192]; \
    u4v r0 = wlo[fb], r1 = wlo[fb+64], r2 = wlo[fb+128], r3 = wlo[fb+192]; \
    float bv = B2l[t*16 + ln]; \
    f4v c0 = {bv,bv,bv,bv}, c1 = c0; \
    s8v bh, bl; \
    bh = __builtin_bit_cast(s8v, g0); bl = __builtin_bit_cast(s8v, r0); \
    c0 = mfma16(FH00, bh, c0); c0 = mfma16(FL00, bh, c0); c0 = mfma16(FH00, bl, c0); \
    c1 = mfma16(FH10, bh, c1); c1 = mfma16(FL10, bh, c1); c1 = mfma16(FH10, bl, c1); \
    bh = __builtin_bit_cast(s8v, g1); bl = __builtin_bit_cast(s8v, r1); \
    c0 = mfma16(FH01, bh, c0); c0 = mfma16(FL01, bh, c0); c0 = mfma16(FH01, bl, c0); \
    c1 = mfma16(FH11, bh, c1); c1 = mfma16(FL11, bh, c1); c1 = mfma16(FH11, bl, c1); \
    bh = __builtin_bit_cast(s8v, g2); bl = __builtin_bit_cast(s8v, r2); \
    c0 = mfma16(FH02, bh, c0); c0 = mfma16(FL02, bh, c0); c0 = mfma16(FH02, bl, c0); \
    c1 = mfma16(FH12, bh, c1); c1 = mfma16(FL12, bh, c1); c1 = mfma16(FH12, bl, c1); \
    bh = __builtin_bit_cast(s8v, g3); bl = __builtin_bit_cast(s8v, r3); \
    c0 = mfma16(FH03, bh, c0); c0 = mfma16(FL03, bh, c0); c0 = mfma16(FH03, bl, c0); \
    c1 = mfma16(FH13, bh, c1); c1 = mfma16(FL13, bh, c1); c1 = mfma16(FH13, bl, c1); \
    ea0 = wgt2 * (ea0 + sin_om(c0.x)); \
    ea1 = wgt2 * (ea1 + sin_om(c0.y)); \
    ea2 = wgt2 * (ea2 + sin_om(c0.z)); \
    ea3 = wgt2 * (ea3 + sin_om(c0.w)); \
    eb0 = wgt2 * (eb0 + sin_om(c1.x)); \
    eb1 = wgt2 * (eb1 + sin_om(c1.y)); \
    eb2 = wgt2 * (eb2 + sin_om(c1.z)); \
    eb3 = wgt2 * (eb3 + sin_om(c1.w)); }

    for (int i = 0; i < NRES; ++i) {
        const int L1 = 2 * i, L2 = 2 * i + 1;
        const float* __restrict__ B1l = b1p + i * HID;
        const float* __restrict__ B2l = b2p + i * HID;
        const float wgt2 = (i == NRES - 1) ? 0.5f : 1.0f;   // ave_second

        LH64(WH)        // h (C-layout regs) -> planes [m][k]
        LAF8(RF)        // h A-fragments

        // ---- matmul1 -> s1 (sine applied), stored back to planes ----
        for (int t = 0; t < 8; ++t) {
            const int fb = (L1*32 + t*4)*64 + lane;
            u4v g0 = whi[fb], g1 = whi[fb+64], g2 = whi[fb+128], g3 = whi[fb+192];
            u4v r0 = wlo[fb], r1 = wlo[fb+64], r2 = wlo[fb+128], r3 = wlo[fb+192];
            float bv = B1l[t*16 + ln];
            f4v c0 = {bv,bv,bv,bv}, c1 = c0;
            s8v bh, bl;
            bh = __builtin_bit_cast(s8v, g0); bl = __builtin_bit_cast(s8v, r0);
            c0 = mfma16(FH00, bh, c0); c0 = mfma16(FL00, bh, c0); c0 = mfma16(FH00, bl, c0);
            c1 = mfma16(FH10, bh, c1); c1 = mfma16(FL10, bh, c1); c1 = mfma16(FH10, bl, c1);
            bh = __builtin_bit_cast(s8v, g1); bl = __builtin_bit_cast(s8v, r1);
            c0 = mfma16(FH01, bh, c0); c0 = mfma16(FL01, bh, c0); c0 = mfma16(FH01, bl, c0);
            c1 = mfma16(FH11, bh, c1); c1 = mfma16(FL11, bh, c1); c1 = mfma16(FH11, bl, c1);
            bh = __builtin_bit_cast(s8v, g2); bl = __builtin_bit_cast(s8v, r2);
            c0 = mfma16(FH02, bh, c0); c0 = mfma16(FL02, bh, c0); c0 = mfma16(FH02, bl, c0);
            c1 = mfma16(FH12, bh, c1); c1 = mfma16(FL12, bh, c1); c1 = mfma16(FH12, bl, c1);
            bh = __builtin_bit_cast(s8v, g3); bl = __builtin_bit_cast(s8v, r3);
            c0 = mfma16(FH03, bh, c0); c0 = mfma16(FL03, bh, c0); c0 = mfma16(FH03, bl, c0);
            c1 = mfma16(FH13, bh, c1); c1 = mfma16(FL13, bh, c1); c1 = mfma16(FH13, bl, c1);
            const int cb = t * 16 + ln;
            SPLIT(sin_om(c0.x), (q4 + 0) * RSTR + cb)
            SPLIT(sin_om(c0.y), (q4 + 1) * RSTR + cb)
            SPLIT(sin_om(c0.z), (q4 + 2) * RSTR + cb)
            SPLIT(sin_om(c0.w), (q4 + 3) * RSTR + cb)
            SPLIT(sin_om(c1.x), (16 + q4 + 0) * RSTR + cb)
            SPLIT(sin_om(c1.y), (16 + q4 + 1) * RSTR + cb)
            SPLIT(sin_om(c1.z), (16 + q4 + 2) * RSTR + cb)
            SPLIT(sin_om(c1.w), (16 + q4 + 3) * RSTR + cb)
        }

        LAF8(RF)        // s1 A-fragments

        // ---- matmul2 -> s2; epilogue h = wgt2*(h + s2) ----
        LT8(ST5)
    }

    // ---- final linear head (fp32 VALU + shuffle reduce over ln) ----
#define LWF(nt) float WF##nt = wfp[nt*16+ln];
    LNT8(LWF)
#define HP(mt,reg) float P_##mt##_##reg = 0.f;
    LMR8(HP)
#define HACC(mt,nt,reg) P_##mt##_##reg = fmaf(WF##nt, H_##mt##_##nt##_##reg, P_##mt##_##reg);
    LH64(HACC)
#define HR(mt,reg) \
    P_##mt##_##reg += __shfl_xor(P_##mt##_##reg, 1); \
    P_##mt##_##reg += __shfl_xor(P_##mt##_##reg, 2); \
    P_##mt##_##reg += __shfl_xor(P_##mt##_##reg, 4); \
    P_##mt##_##reg += __shfl_xor(P_##mt##_##reg, 8);
    LMR8(HR)
    const float bf0 = bfp[0];
    if (ln == 0) {
#define HS(mt,reg) { int pt_ = base_pt + mt*16 + q4 + reg; \
        if (pt_ < NP) out[pt_] = P_##mt##_##reg + bf0; }
        LMR8(HS)
    }
}

extern "C" void kernel_launch(void* const* d_in, const int* in_sizes, int n_in,
                              void* d_out, int out_size, void* d_ws, size_t ws_size,
                              hipStream_t stream) {
    const float* x   = (const float*)d_in[0];
    const float* w0  = (const float*)d_in[1];
    const float* b0  = (const float*)d_in[2];
    const float* rw1 = (const float*)d_in[3];
    const float* rb1 = (const float*)d_in[4];
    const float* rw2 = (const float*)d_in[5];
    const float* rb2 = (const float*)d_in[6];
    const float* wf  = (const float*)d_in[7];
    const float* bf  = (const float*)d_in[8];
    float* out = (float*)d_out;

    unsigned short* wsHi = (unsigned short*)d_ws;          // needs 917504 B
    unsigned short* wsLo = wsHi + FRAG_ELEMS;

    const int n = in_sizes[0] / 3;                          // 200000
    prep_kernel<<<112, 256, 0, stream>>>(rw1, rw2, wsHi, wsLo);
    const int grid = (n + 31) / 32;                         // 6250 waves
    siren_mfma<<<grid, BT, 0, stream>>>(x, w0, b0, rb1, rb2, wf, bf,
                                        (const u4v*)wsHi, (const u4v*)wsLo,
                                        out, n);
}